// Round 1
// 339.916 us; speedup vs baseline: 1.0530x; 1.0530x over previous
//
#include <hip/hip_runtime.h>
#include <hip/hip_bf16.h>

#define DEPTH 2
#define DIM   1024
#define SDIM  256
#define BATCH 256
#define SHOTS 64
#define M_TOT (BATCH*SHOTS)   // 16384
#define NCH   8               // scan chunks
#define CH    (SHOTS/NCH)     // 8 steps per chunk

typedef __attribute__((ext_vector_type(8))) short bf16x8;  // 8 bf16 = 4 VGPRs
typedef __attribute__((ext_vector_type(4))) float f32x4;
typedef unsigned short u16;

__device__ __forceinline__ u16 f2bf(float f) {
    union { float f; unsigned u; } v; v.f = f;
    unsigned r = v.u + 0x7fffu + ((v.u >> 16) & 1u);
    return (u16)(r >> 16);
}

__device__ __forceinline__ unsigned pk_bf2(float a, float b) {
    union { __hip_bfloat162 h2; unsigned u; } c;
    c.h2 = __float22bfloat162_rn(make_float2(a, b));   // v_cvt_pk_bf16_f32
    return c.u;
}

__device__ __forceinline__ float softplus_f(float x) {
    if (x > 20.f) return x;
    return log1pf(__expf(x));
}

// async global->LDS, 16B per lane (global_load_lds_dwordx4)
__device__ __forceinline__ void gld16(const u16* g, u16* l) {
    __builtin_amdgcn_global_load_lds(
        (const __attribute__((address_space(1))) unsigned int*)g,
        (__attribute__((address_space(3))) unsigned int*)l, 16, 0, 0);
}

// ---------------------------------------------------------------------------
// transpose_conv: out[n][k] (bf16) = in[k][n] (fp32), dual-source split over n.
// ---------------------------------------------------------------------------
__global__ __launch_bounds__(256)
void transpose_conv(const float* __restrict__ A1, const float* __restrict__ A2,
                    u16* __restrict__ out, int K, int N, int SPLIT)
{
    __shared__ float T[64][65];
    const int layer = blockIdx.z;
    const int k0 = blockIdx.x * 64, n0 = blockIdx.y * 64;
    const int tid = threadIdx.x;

    const bool first = (n0 < SPLIT);
    const int scols = first ? SPLIT : (N - SPLIT);
    const float* S = (first ? A1 : A2) + (size_t)layer * K * scols
                     + (first ? n0 : (n0 - SPLIT));
    out += (size_t)layer * K * N;

    #pragma unroll
    for (int i = 0; i < 4; ++i) {
        const int c = tid + i * 256;
        const int kr = c >> 4, cc = c & 15;
        const float4 v = *(const float4*)(S + (size_t)(k0 + kr) * scols + cc * 4);
        T[kr][cc * 4 + 0] = v.x; T[kr][cc * 4 + 1] = v.y;
        T[kr][cc * 4 + 2] = v.z; T[kr][cc * 4 + 3] = v.w;
    }
    __syncthreads();
    #pragma unroll
    for (int i = 0; i < 4; ++i) {
        const int c = tid + i * 256;
        const int nr = c >> 4, cc = c & 15;
        ushort4 h;
        h.x = f2bf(T[cc * 4 + 0][nr]); h.y = f2bf(T[cc * 4 + 1][nr]);
        h.z = f2bf(T[cc * 4 + 2][nr]); h.w = f2bf(T[cc * 4 + 3][nr]);
        *(ushort4*)&out[(size_t)(n0 + nr) * K + k0 + cc * 4] = h;
    }
}

// ---------------------------------------------------------------------------
// conv_bf16: fp32 -> bf16 pack, 8 elems/thread (one-time X0 conversion).
// ---------------------------------------------------------------------------
__global__ __launch_bounds__(256)
void conv_bf16(const float* __restrict__ in, u16* __restrict__ out)
{
    const size_t total = (size_t)M_TOT * DIM;
    const size_t stride = (size_t)gridDim.x * 256 * 8;
    for (size_t i = ((size_t)blockIdx.x * 256 + threadIdx.x) * 8; i < total; i += stride) {
        const float4 a = *(const float4*)(in + i);
        const float4 b = *(const float4*)(in + i + 4);
        int4 o;
        o.x = (int)pk_bf2(a.x, a.y); o.y = (int)pk_bf2(a.z, a.w);
        o.z = (int)pk_bf2(b.x, b.y); o.w = (int)pk_bf2(b.z, b.w);
        *(int4*)(out + i) = o;
    }
}

#define BM 128
#define BN 128
#define BK 32

// ---------------------------------------------------------------------------
// gemm_bf16: C[M,N] = A[M,K] @ BT[N,K]^T, bf16 MFMA 16x16x32, m97 structure:
// 128x128 tile, linear LDS [128][32], width-16 global_load_lds staging.
// EPI: 0 none, 1 +bias, 2 +bias+cs[row/64]. BF16OUT: write bf16 instead of f32.
// SWIZ: XCD-aware block swizzle.
// ---------------------------------------------------------------------------
template<int EPI, bool SWIZ, bool BF16OUT>
__global__ __launch_bounds__(256)
void gemm_bf16(const u16* __restrict__ A, const u16* __restrict__ BT,
               void* __restrict__ Cv, const float* __restrict__ bo,
               const float* __restrict__ cs, int K, int ldc, int CB)
{
    __shared__ __align__(16) u16 As[BM * BK];   // 8 KiB
    __shared__ __align__(16) u16 Bs[BN * BK];   // 8 KiB

    const int tid = threadIdx.x;
    const int id  = blockIdx.x;
    int rb, cb;
    if (SWIZ) {
        const int xcd = id & 7, slot = id >> 3;
        rb = xcd + 8 * (slot / CB);
        cb = slot % CB;
    } else {
        rb = id / CB; cb = id % CB;
    }
    const int row0 = rb * BM, col0 = cb * BN;

    const int l  = tid & 63;
    const int w  = tid >> 6;
    const int wm = (w >> 1) * 64, wn = (w & 1) * 64;
    const int lr = l & 15, lq = l >> 4;

    // staging geometry: wave w covers row-groups {2w, 2w+1}, 16 rows each.
    // lane l -> row (l>>2) within group, bf16 col (l&3)*8 (16 B).
    // LDS dest = group*1024 B + l*16 B == linear row-major [128][32].
    const int sg   = w * 2;
    const int srow = l >> 2;
    const int scol = (l & 3) * 8;
    const u16* Ag = A  + (size_t)(row0 + sg * 16 + srow) * K + scol;
    const u16* Bg = BT + (size_t)(col0 + sg * 16 + srow) * K + scol;
    u16* Asd = &As[sg * 512 + l * 8];
    u16* Bsd = &Bs[sg * 512 + l * 8];

    f32x4 acc[4][4];
    #pragma unroll
    for (int i = 0; i < 4; ++i)
        #pragma unroll
        for (int j = 0; j < 4; ++j)
            acc[i][j] = (f32x4){0.f, 0.f, 0.f, 0.f};

    for (int k0 = 0; k0 < K; k0 += BK) {
        gld16(Ag + k0,                  Asd);
        gld16(Ag + (size_t)16 * K + k0, Asd + 512);
        gld16(Bg + k0,                  Bsd);
        gld16(Bg + (size_t)16 * K + k0, Bsd + 512);
        __syncthreads();

        bf16x8 af[4], bfr[4];
        #pragma unroll
        for (int i = 0; i < 4; ++i)
            af[i] = *(const bf16x8*)&As[(wm + i * 16 + lr) * BK + lq * 8];
        #pragma unroll
        for (int j = 0; j < 4; ++j)
            bfr[j] = *(const bf16x8*)&Bs[(wn + j * 16 + lr) * BK + lq * 8];

        #pragma unroll
        for (int i = 0; i < 4; ++i)
            #pragma unroll
            for (int j = 0; j < 4; ++j)
                acc[i][j] = __builtin_amdgcn_mfma_f32_16x16x32_bf16(
                    af[i], bfr[j], acc[i][j], 0, 0, 0);
        __syncthreads();
    }

    // epilogue: C/D layout col=lane&15, row=quad*4+reg
    #pragma unroll
    for (int i = 0; i < 4; ++i) {
        const int grow = row0 + wm + i * 16 + lq * 4;
        #pragma unroll
        for (int j = 0; j < 4; ++j) {
            const int gcol = col0 + wn + j * 16 + lr;
            float addv = 0.f;
            if (EPI >= 1) addv += bo[gcol];
            if (EPI == 2) addv += cs[(size_t)(grow >> 6) * DIM + gcol];
            if (BF16OUT) {
                u16* Cb = (u16*)Cv;
                #pragma unroll
                for (int r = 0; r < 4; ++r)
                    Cb[(size_t)(grow + r) * ldc + gcol] = f2bf(acc[i][j][r] + addv);
            } else {
                float* C = (float*)Cv;
                #pragma unroll
                for (int r = 0; r < 4; ++r)
                    C[(size_t)(grow + r) * ldc + gcol] = acc[i][j][r] + addv;
            }
        }
    }
}

// ---------------------------------------------------------------------------
// scan_phaseA: per (b, chunk c, n): read raw P,Q; compute dec/drv inline;
// compose 8 steps -> (prod_decay, h_from_zero_state).
// PQ: [M_TOT, 512] fp32 (P = cols 0..255, Q = cols 256..511).
// ---------------------------------------------------------------------------
__global__ __launch_bounds__(256)
void scan_phaseA(const float* __restrict__ PQ,
                 const float* __restrict__ bd, const float* __restrict__ bi,
                 const float* __restrict__ A_log, float2* __restrict__ sums)
{
    const int b = blockIdx.x, c = blockIdx.y, n = threadIdx.x;
    const float bdv = bd[n], biv = bi[n];
    const float spA = softplus_f(A_log[n]);
    const size_t m0 = (size_t)b * SHOTS + c * CH;
    float a = 1.f, h = 0.f;
    #pragma unroll
    for (int s = 0; s < CH; ++s) {
        const float* row = PQ + (m0 + s) * 512;
        const float delta = softplus_f(row[n] + bdv);
        const float dec = __expf(-delta * spA);
        const float drv = delta * (row[n + SDIM] + biv);
        a *= dec;
        h = dec * h + drv;
    }
    sums[((size_t)b * NCH + c) * SDIM + n] = make_float2(a, h);
}

// ---------------------------------------------------------------------------
// scan_phaseC: compose prefix from chunk summaries, replay 8 steps (recompute
// dec/drv), write hs (bf16) and final state (last chunk, bf16).
// ---------------------------------------------------------------------------
__global__ __launch_bounds__(256)
void scan_phaseC(const float* __restrict__ PQ, const float2* __restrict__ sums,
                 const float* __restrict__ bd, const float* __restrict__ bi,
                 const float* __restrict__ A_log,
                 u16* __restrict__ hsb, u16* __restrict__ stateb)
{
    const int b = blockIdx.x, c = blockIdx.y, n = threadIdx.x;
    const float bdv = bd[n], biv = bi[n];
    const float spA = softplus_f(A_log[n]);
    float h = 0.f;
    for (int j = 0; j < c; ++j) {
        const float2 sv = sums[((size_t)b * NCH + j) * SDIM + n];
        h = sv.x * h + sv.y;
    }
    const size_t m0 = (size_t)b * SHOTS + c * CH;
    #pragma unroll
    for (int s = 0; s < CH; ++s) {
        const float* row = PQ + (m0 + s) * 512;
        const float delta = softplus_f(row[n] + bdv);
        const float dec = __expf(-delta * spA);
        const float drv = delta * (row[n + SDIM] + biv);
        h = dec * h + drv;
        hsb[(m0 + s) * SDIM + n] = f2bf(h);
    }
    if (c == NCH - 1) stateb[(size_t)b * SDIM + n] = f2bf(h);
}

// ---------------------------------------------------------------------------
// final_kernel: pooled = class_state + mean_s(hidden); LayerNorm.
// ---------------------------------------------------------------------------
__global__ __launch_bounds__(1024)
void final_kernel(const float* __restrict__ hidden, const float* __restrict__ cs,
                  const float* __restrict__ gamma, const float* __restrict__ beta,
                  float* __restrict__ out)
{
    const int b = blockIdx.x;
    const int d = threadIdx.x;

    float acc = 0.f;
    #pragma unroll 4
    for (int s = 0; s < SHOTS; ++s)
        acc += hidden[((size_t)(b * SHOTS + s)) * DIM + d];
    const float p = cs[(size_t)b * DIM + d] + acc * (1.f / SHOTS);

    __shared__ float rsum[1024], rsq[1024];
    rsum[d] = p; rsq[d] = p * p;
    __syncthreads();
    for (int off = 512; off > 0; off >>= 1) {
        if (d < off) { rsum[d] += rsum[d + off]; rsq[d] += rsq[d + off]; }
        __syncthreads();
    }
    const float mu  = rsum[0] * (1.f / DIM);
    const float var = rsq[0] * (1.f / DIM) - mu * mu;
    const float inv = rsqrtf(var + 1e-5f);

    out[(size_t)b * DIM + d] = (p - mu) * inv * gamma[d] + beta[d];
}

// ---------------------------------------------------------------------------

extern "C" void kernel_launch(void* const* d_in, const int* in_sizes, int n_in,
                              void* d_out, int out_size, void* d_ws, size_t ws_size,
                              hipStream_t stream)
{
    const float* X0    = (const float*)d_in[0];
    const float* Wd    = (const float*)d_in[1];
    const float* bd    = (const float*)d_in[2];
    const float* Wi    = (const float*)d_in[3];
    const float* bi    = (const float*)d_in[4];
    const float* A_log = (const float*)d_in[5];
    const float* Wo    = (const float*)d_in[6];
    const float* bo    = (const float*)d_in[7];
    const float* Ws    = (const float*)d_in[8];
    const float* bs    = (const float*)d_in[9];
    const float* gamma = (const float*)d_in[10];
    const float* beta  = (const float*)d_in[11];

    float* out_cr     = (float*)d_out;                  // [BATCH, DIM]
    float* out_hidden = out_cr + (size_t)BATCH * DIM;   // [BATCH, SHOTS, DIM] fp32

    // Xbf (bf16 activations for the next layer's A) lives in the out_hidden
    // region as scratch: 33.5 MB needed, 67 MB available. It is dead before
    // the layer-1 hidden GEMM performs the final fp32 write of out_hidden.
    u16* Xbf = (u16*)out_hidden;

    // ws layout: 51,511,296 B <= proven 51,642,368 B footprint
    char* w = (char*)d_ws;
    float*  PQ     = (float*)w;  w += (size_t)M_TOT * 512 * 4;          // 33.55 MB
    float2* sums   = (float2*)w; w += (size_t)BATCH * NCH * SDIM * 8;   //  4.19 MB
    float*  csbuf  = (float*)w;  w += (size_t)BATCH * DIM * 4;          //  1.05 MB
    u16*    stateb = (u16*)w;    w += (size_t)BATCH * SDIM * 2;         //  0.13 MB
    u16*    hsb    = (u16*)w;    w += (size_t)M_TOT * SDIM * 2;         //  8.39 MB
    u16*    WcombT = (u16*)w;    w += (size_t)DEPTH * 512 * 1024 * 2;   //  2.10 MB
    u16*    WoT    = (u16*)w;    w += (size_t)DEPTH * 1024 * 256 * 2;   //  1.05 MB
    u16*    WsT    = (u16*)w;    w += (size_t)DEPTH * 1024 * 256 * 2;   //  1.05 MB

    // one-time weight transpose+convert
    transpose_conv<<<dim3(1024 / 64, 512 / 64, DEPTH), 256, 0, stream>>>(
        Wd, Wi, WcombT, 1024, 512, 256);   // rows 0-255: WdT, 256-511: WiT
    transpose_conv<<<dim3(256 / 64, 1024 / 64, DEPTH), 256, 0, stream>>>(
        Wo, Wo, WoT, 256, 1024, 1024);
    transpose_conv<<<dim3(256 / 64, 1024 / 64, DEPTH), 256, 0, stream>>>(
        Ws, Ws, WsT, 256, 1024, 1024);
    // one-time input conversion fp32 -> bf16
    conv_bf16<<<2048, 256, 0, stream>>>(X0, Xbf);

    for (int l = 0; l < DEPTH; ++l) {
        // PQ = Xbf @ [Wd|Wi]  (M=16384, N=512, K=1024): grid 512 -> 2 blocks/CU
        gemm_bf16<0, true, false><<<512, 256, 0, stream>>>(
            Xbf, WcombT + (size_t)l * 512 * 1024, PQ, nullptr, nullptr,
            1024, 512, 4);
        // chunked scan with inline decay/drive
        scan_phaseA<<<dim3(BATCH, NCH), SDIM, 0, stream>>>(
            PQ, bd + l * SDIM, bi + l * SDIM, A_log + l * SDIM, sums);
        scan_phaseC<<<dim3(BATCH, NCH), SDIM, 0, stream>>>(
            PQ, sums, bd + l * SDIM, bi + l * SDIM, A_log + l * SDIM, hsb, stateb);
        // class_state = state @ Ws + bs  (M=256, N=1024, K=256)
        gemm_bf16<1, false, false><<<16, 256, 0, stream>>>(
            stateb, WsT + (size_t)l * 1024 * 256, csbuf, bs + l * DIM, nullptr,
            256, 1024, 8);
        // hidden = hs @ Wo + bo + class_state  (M=16384, N=1024, K=256)
        if (l < DEPTH - 1) {
            // intermediate layer: hidden is only consumed as next-layer A -> bf16 only
            gemm_bf16<2, true, true><<<1024, 256, 0, stream>>>(
                hsb, WoT + (size_t)l * 1024 * 256, Xbf, bo + l * DIM, csbuf,
                256, 1024, 8);
        } else {
            // last layer: fp32 hidden is a kernel output
            gemm_bf16<2, true, false><<<1024, 256, 0, stream>>>(
                hsb, WoT + (size_t)l * 1024 * 256, out_hidden, bo + l * DIM, csbuf,
                256, 1024, 8);
        }
    }
    final_kernel<<<BATCH, 1024, 0, stream>>>(out_hidden, csbuf, gamma, beta, out_cr);
}